// Round 1
// baseline (138.383 us; speedup 1.0000x reference)
//
#include <hip/hip_runtime.h>
#include <math.h>

// AutoAttention_Layer: B=1024, MAXLEN=200, F=64, D=64, fp32.
// Algebra: v unused; the three DxD projections collapse to per-batch 64-GEMVs
// (qbar = sum_f fs[f] q[b,f,:]; qw = qbar@Wq; qk = Wk@qw; out = kbar@Wv);
// single-pass softmax: unmasked logits = sigmoid(.)/8 in (0,0.125) -> exp needs
// no max-shift; masked exp underflows to exactly 0; len==0 -> uniform weights.
//
// R1 change vs verified 138.5us version: FULL k PRELOAD. The grid is entirely
// resident (1024 blocks = 4/CU exactly), so runtime ~= one block's serial
// chain. Previous loop used prefetch depth 1: each chunk's HBM load (~900cy)
// was covered by only ~100cy of compute. Now all nc chunks (<=4, 64 VGPRs)
// are loaded at kernel entry, before the 6-barrier GEMV chain -- k latency
// fully overlaps the qbar->qw->qk pipeline; the main loop is pure-register.
// Chunk loop fully unrolled with wave-uniform guards so kreg indices are
// compile-time (runtime-indexed arrays would spill to scratch).

namespace {
constexpr int MAXLEN = 200;

__global__ __launch_bounds__(256, 4)   // 4 waves/EU -> 4 blocks/CU; VGPR cap 128
void auto_attn_kernel(const float* __restrict__ q,
                      const float* __restrict__ k,
                      const int*   __restrict__ kes_length,
                      const float* __restrict__ fs,
                      const float* __restrict__ bias,
                      const float* __restrict__ Wq,
                      const float* __restrict__ Wk,
                      const float* __restrict__ Wv,
                      float*       __restrict__ out)
{
    __shared__ float red[256];
    __shared__ float vec[64];          // qbar -> qw -> kbar (reused across barriers)
    __shared__ float qks[64];
    __shared__ float scr[64 * 65];     // token-partial kacc transpose (pad 65: <=2-way)
    __shared__ float sS[4];

    const int tid  = threadIdx.x;
    const int b    = blockIdx.x;
    const int lane = tid & 63;
    const int wave = tid >> 6;
    const int tok  = tid >> 2;         // 0..63: token slot
    const int dq   = (tid & 3) << 4;   // 16-float slice of D

    const float* kb = k + (size_t)b * (MAXLEN * 64);
    const float* qb = q + (size_t)b * (64 * 64);   // F == D == 64

    const int len = kes_length[b];
    // chunks actually contributing: len==0 -> all 4 (uniform softmax);
    // else ceil(len/64) (tokens >= len have weight exactly 0)
    const int nc = (len == 0) ? 4 : min(4, (len + 63) >> 6);

    // ---- preload ALL needed k chunks into registers, before the GEMV chain.
    // Wave-uniform guard (nc depends only on b); static indices -> stays in
    // VGPRs. Tokens >= MAXLEN (chunk 3, tok >= 8) load a clamped in-bounds
    // address: finite garbage, contribution killed exactly by w == 0.
    float4 kreg[4][4];
    #pragma unroll
    for (int c = 0; c < 4; ++c) {
        if (c < nc) {
            const int t  = c * 64 + tok;
            const int tc = (t < MAXLEN) ? t : (MAXLEN - 1);
            const float4* kr = (const float4*)(kb + tc * 64 + dq);
            kreg[c][0] = kr[0]; kreg[c][1] = kr[1];
            kreg[c][2] = kr[2]; kreg[c][3] = kr[3];
        }
    }

    // ---- qbar[d] = sum_f fs[f] * q[b,f,d]
    float acc = 0.f;
    #pragma unroll
    for (int i = 0; i < 16; ++i) {
        const int f = wave * 16 + i;
        acc += fs[f] * qb[f * 64 + lane];
    }
    red[tid] = acc;
    __syncthreads();
    if (tid < 64) vec[tid] = red[tid] + red[tid + 64] + red[tid + 128] + red[tid + 192];
    __syncthreads();

    // ---- qw[e] = sum_d qbar[d] * Wq[d,e]
    acc = 0.f;
    #pragma unroll
    for (int i = 0; i < 16; ++i) {
        const int dd = wave * 16 + i;
        acc += vec[dd] * Wq[dd * 64 + lane];
    }
    red[tid] = acc;
    __syncthreads();
    if (tid < 64) vec[tid] = red[tid] + red[tid + 64] + red[tid + 128] + red[tid + 192];
    __syncthreads();

    // ---- qk[d] = sum_e Wk[d,e] * qw[e]   (Wk 16 KB, L1/L2-hot across blocks)
    acc = 0.f;
    #pragma unroll
    for (int i = 0; i < 16; ++i) {
        const int e = wave * 16 + i;
        acc += Wk[lane * 64 + e] * vec[e];
    }
    red[tid] = acc;
    __syncthreads();
    if (tid < 64) qks[tid] = red[tid] + red[tid + 64] + red[tid + 128] + red[tid + 192];
    __syncthreads();

    // each thread's 16-float slice of qk -> registers (broadcast reads, free)
    float qkreg[16];
    {
        const float4* qp = (const float4*)(qks + dq);
        #pragma unroll
        for (int j = 0; j < 4; ++j) {
            const float4 t4 = qp[j];
            qkreg[j*4+0] = t4.x; qkreg[j*4+1] = t4.y;
            qkreg[j*4+2] = t4.z; qkreg[j*4+3] = t4.w;
        }
    }

    const float bscale = bias[0] * 64.0f;

    // ---- main loop: pure register compute, no memory, no barriers.
    float kacc[16];
    #pragma unroll
    for (int i = 0; i < 16; ++i) kacc[i] = 0.f;
    float Sr = 0.f;

    #pragma unroll
    for (int c = 0; c < 4; ++c) {
        if (c < nc) {                         // wave-uniform
            const int t = c * 64 + tok;
            const float* cf = (const float*)kreg[c];
            // 4-way split dot for ILP (16-deep FMA chain -> 4-deep)
            float s0 = 0.f, s1 = 0.f, s2 = 0.f, s3 = 0.f;
            #pragma unroll
            for (int i = 0; i < 4; ++i) {
                s0 += cf[i]      * qkreg[i];
                s1 += cf[i + 4]  * qkreg[i + 4];
                s2 += cf[i + 8]  * qkreg[i + 8];
                s3 += cf[i + 12] * qkreg[i + 12];
            }
            float s = (s0 + s1) + (s2 + s3);
            s += __shfl_xor(s, 1);            // combine the 4 slice-lanes
            s += __shfl_xor(s, 2);
            s += bscale;
            float w = 0.f;
            if (t < MAXLEN) {
                if (len == 0)      w = 1.0f;                          // uniform softmax
                else if (t < len) { const float sig = 1.0f / (1.0f + __expf(-s));
                                    w = __expf(sig * 0.125f); }       // no max-shift
                // else masked: w stays 0 (exact)
            }
            #pragma unroll
            for (int i = 0; i < 16; ++i) kacc[i] += w * cf[i];
            Sr += w;                          // slice-redundant; reduced over toks only
        }
    }

    // ---- S = sum_t w  (reduce across the 16 tokens of each wave, then 4 waves)
    float Sw = Sr;
    Sw += __shfl_xor(Sw, 4);
    Sw += __shfl_xor(Sw, 8);
    Sw += __shfl_xor(Sw, 16);
    Sw += __shfl_xor(Sw, 32);
    if (lane == 0) sS[wave] = Sw;

    // ---- reduce kacc across the 64 token slots via LDS transpose
    #pragma unroll
    for (int i = 0; i < 16; ++i) scr[tok * 65 + dq + i] = kacc[i];
    __syncthreads();
    const float S = sS[0] + sS[1] + sS[2] + sS[3];     // >= 1 always
    acc = 0.f;
    #pragma unroll
    for (int i = 0; i < 16; ++i) {
        const int row = wave * 16 + i;
        acc += scr[row * 65 + lane];       // banks (row+lane)%32 -> 2-way, free
    }
    red[tid] = acc;
    __syncthreads();
    if (tid < 64)
        vec[tid] = (red[tid] + red[tid + 64] + red[tid + 128] + red[tid + 192]) / S;
    __syncthreads();

    // ---- out[b] = kbar @ Wv
    acc = 0.f;
    #pragma unroll
    for (int i = 0; i < 16; ++i) {
        const int dd = wave * 16 + i;
        acc += vec[dd] * Wv[dd * 64 + lane];
    }
    red[tid] = acc;
    __syncthreads();
    if (tid < 64)
        out[(size_t)b * 64 + tid] = red[tid] + red[tid + 64] + red[tid + 128] + red[tid + 192];
}
} // namespace

extern "C" void kernel_launch(void* const* d_in, const int* in_sizes, int n_in,
                              void* d_out, int out_size, void* d_ws, size_t ws_size,
                              hipStream_t stream) {
    const float* q    = (const float*)d_in[0];
    const float* k    = (const float*)d_in[1];
    // d_in[2] = v : unused by the reference (vp is computed from k)
    const int*   kes  = (const int*)  d_in[3];
    const float* fs   = (const float*)d_in[4];
    const float* bias = (const float*)d_in[5];
    const float* Wq   = (const float*)d_in[6];
    const float* Wk   = (const float*)d_in[7];
    const float* Wv   = (const float*)d_in[8];
    float* out = (float*)d_out;

    auto_attn_kernel<<<dim3(1024), dim3(256), 0, stream>>>(q, k, kes, fs, bias, Wq, Wk, Wv, out);
}

// Round 2
// 137.486 us; speedup vs baseline: 1.0065x; 1.0065x over previous
//
#include <hip/hip_runtime.h>
#include <math.h>

// AutoAttention_Layer: B=1024, MAXLEN=200, F=64, D=64, fp32.
// Algebra: v unused; the three DxD projections collapse to per-batch 64-GEMVs
// (qbar = sum_f fs[f] q[b,f,:]; qw = qbar@Wq; qk = Wk@qw; out = kbar@Wv);
// single-pass softmax: unmasked logits = sigmoid(.)/8 in (0,0.125) -> exp needs
// no max-shift; masked exp underflows to exactly 0; len==0 -> uniform weights.
//
// R2 changes (theory: HBM-traffic-bound at ~3.7 TB/s effective):
//  1. EXACT-LEN k skip: previously the tail chunk loaded all 64 tokens even
//     when only len%64 contribute (avg waste ~33 rows x 256B x 1024 batches
//     ~= 8.8 MB of ~51 MB total, -17%). Now each token slot loads only if
//     t < len (or len==0 uniform path). Skipped slots are ZERO-INITIALIZED
//     (not just weight-0): 0 * uninitialized-register could be NaN; 0*0 is
//     exact and w==0 makes the contribution exactly zero either way.
//  2. q phase vectorized to float4 (16B/lane, 4 loads/thread instead of 16
//     scalar): coalescing sweet spot, shorter issue chain. Partial sums go
//     through scr (reused as float4[256] scratch before its transpose use).

namespace {
constexpr int MAXLEN = 200;

__global__ __launch_bounds__(256, 4)   // 4 waves/EU -> 4 blocks/CU; VGPR cap 128
void auto_attn_kernel(const float* __restrict__ q,
                      const float* __restrict__ k,
                      const int*   __restrict__ kes_length,
                      const float* __restrict__ fs,
                      const float* __restrict__ bias,
                      const float* __restrict__ Wq,
                      const float* __restrict__ Wk,
                      const float* __restrict__ Wv,
                      float*       __restrict__ out)
{
    __shared__ float red[256];
    __shared__ float vec[64];          // qbar -> qw -> kbar (reused across barriers)
    __shared__ float qks[64];
    __shared__ __align__(16) float scr[64 * 65];  // q-phase float4 scratch, then kacc transpose
    __shared__ float sS[4];

    const int tid  = threadIdx.x;
    const int b    = blockIdx.x;
    const int lane = tid & 63;
    const int wave = tid >> 6;
    const int tok  = tid >> 2;         // 0..63: token slot
    const int dq   = (tid & 3) << 4;   // 16-float slice of D

    const float* kb = k + (size_t)b * (MAXLEN * 64);
    const float* qb = q + (size_t)b * (64 * 64);   // F == D == 64

    const int len = kes_length[b];
    const bool uni = (len == 0);       // len==0 -> uniform softmax over all 200
    // chunks containing any contributing token
    const int nc = uni ? 4 : min(4, (len + 63) >> 6);

    // ---- preload contributing k rows into registers (before the GEMV chain,
    // so HBM latency overlaps it). Exact-len: token slots past len load
    // nothing and are zeroed. Wave-uniform outer guard (nc), per-lane inner
    // guard (exec-masked loads). Static indices -> stays in VGPRs.
    float4 kreg[4][4];
    #pragma unroll
    for (int c = 0; c < 4; ++c) {
        if (c < nc) {
            const int t = c * 64 + tok;
            const bool valid = (t < MAXLEN) && (uni || t < len);
            if (valid) {
                const float4* kr = (const float4*)(kb + t * 64 + dq);
                kreg[c][0] = kr[0]; kreg[c][1] = kr[1];
                kreg[c][2] = kr[2]; kreg[c][3] = kr[3];
            } else {
                const float4 z = make_float4(0.f, 0.f, 0.f, 0.f);
                kreg[c][0] = z; kreg[c][1] = z; kreg[c][2] = z; kreg[c][3] = z;
            }
        }
    }

    // ---- qbar[d] = sum_f fs[f] * q[b,f,d]   (float4 loads: 16B/lane)
    // thread (wave, fgrp=lane>>4, dsl=lane&15) accumulates d in [4*dsl,4*dsl+3]
    // over f in {wave*16 + i*4 + fgrp, i=0..3}
    {
        const int fgrp = lane >> 4;
        const int dsl  = lane & 15;
        float4 a4 = make_float4(0.f, 0.f, 0.f, 0.f);
        #pragma unroll
        for (int i = 0; i < 4; ++i) {
            const int f = wave * 16 + i * 4 + fgrp;
            const float4 q4 = *(const float4*)(qb + f * 64 + dsl * 4);
            const float s = fs[f];
            a4.x += s * q4.x; a4.y += s * q4.y; a4.z += s * q4.z; a4.w += s * q4.w;
        }
        ((float4*)scr)[tid] = a4;      // scr as float4[256] (4 KB of its 16.6 KB)
    }
    __syncthreads();
    if (tid < 64) {
        // partials for d live at rows w*64 + g*16 + (d>>2), component d&3
        float s = 0.f;
        #pragma unroll
        for (int j = 0; j < 16; ++j) {
            const int row = (j >> 2) * 64 + (j & 3) * 16 + (tid >> 2);
            s += scr[row * 4 + (tid & 3)];   // idx = 4*C + tid: conflict-free
        }
        vec[tid] = s;
    }
    __syncthreads();

    // ---- qw[e] = sum_d qbar[d] * Wq[d,e]
    float acc = 0.f;
    #pragma unroll
    for (int i = 0; i < 16; ++i) {
        const int dd = wave * 16 + i;
        acc += vec[dd] * Wq[dd * 64 + lane];
    }
    red[tid] = acc;
    __syncthreads();
    if (tid < 64) vec[tid] = red[tid] + red[tid + 64] + red[tid + 128] + red[tid + 192];
    __syncthreads();

    // ---- qk[d] = sum_e Wk[d,e] * qw[e]   (Wk 16 KB, L1/L2-hot across blocks)
    acc = 0.f;
    #pragma unroll
    for (int i = 0; i < 16; ++i) {
        const int e = wave * 16 + i;
        acc += Wk[lane * 64 + e] * vec[e];
    }
    red[tid] = acc;
    __syncthreads();
    if (tid < 64) qks[tid] = red[tid] + red[tid + 64] + red[tid + 128] + red[tid + 192];
    __syncthreads();

    // each thread's 16-float slice of qk -> registers (broadcast reads, free)
    float qkreg[16];
    {
        const float4* qp = (const float4*)(qks + dq);
        #pragma unroll
        for (int j = 0; j < 4; ++j) {
            const float4 t4 = qp[j];
            qkreg[j*4+0] = t4.x; qkreg[j*4+1] = t4.y;
            qkreg[j*4+2] = t4.z; qkreg[j*4+3] = t4.w;
        }
    }

    const float bscale = bias[0] * 64.0f;

    // ---- main loop: pure register compute, no memory, no barriers.
    float kacc[16];
    #pragma unroll
    for (int i = 0; i < 16; ++i) kacc[i] = 0.f;
    float Sr = 0.f;

    #pragma unroll
    for (int c = 0; c < 4; ++c) {
        if (c < nc) {                         // wave-uniform
            const int t = c * 64 + tok;
            const float* cf = (const float*)kreg[c];
            // 4-way split dot for ILP (16-deep FMA chain -> 4-deep)
            float s0 = 0.f, s1 = 0.f, s2 = 0.f, s3 = 0.f;
            #pragma unroll
            for (int i = 0; i < 4; ++i) {
                s0 += cf[i]      * qkreg[i];
                s1 += cf[i + 4]  * qkreg[i + 4];
                s2 += cf[i + 8]  * qkreg[i + 8];
                s3 += cf[i + 12] * qkreg[i + 12];
            }
            float s = (s0 + s1) + (s2 + s3);
            s += __shfl_xor(s, 1);            // combine the 4 slice-lanes
            s += __shfl_xor(s, 2);
            s += bscale;
            float w = 0.f;
            if (t < MAXLEN) {
                if (uni)           w = 1.0f;                          // uniform softmax
                else if (t < len) { const float sig = 1.0f / (1.0f + __expf(-s));
                                    w = __expf(sig * 0.125f); }       // no max-shift
                // else masked: w stays 0 (cf is 0 too -> exact)
            }
            #pragma unroll
            for (int i = 0; i < 16; ++i) kacc[i] += w * cf[i];
            Sr += w;                          // slice-redundant; reduced over toks only
        }
    }

    // ---- S = sum_t w  (reduce across the 16 tokens of each wave, then 4 waves)
    float Sw = Sr;
    Sw += __shfl_xor(Sw, 4);
    Sw += __shfl_xor(Sw, 8);
    Sw += __shfl_xor(Sw, 16);
    Sw += __shfl_xor(Sw, 32);
    if (lane == 0) sS[wave] = Sw;

    // ---- reduce kacc across the 64 token slots via LDS transpose
    #pragma unroll
    for (int i = 0; i < 16; ++i) scr[tok * 65 + dq + i] = kacc[i];
    __syncthreads();
    const float S = sS[0] + sS[1] + sS[2] + sS[3];     // >= 1 always
    acc = 0.f;
    #pragma unroll
    for (int i = 0; i < 16; ++i) {
        const int row = wave * 16 + i;
        acc += scr[row * 65 + lane];       // banks (row+lane)%32 -> 2-way, free
    }
    red[tid] = acc;
    __syncthreads();
    if (tid < 64)
        vec[tid] = (red[tid] + red[tid + 64] + red[tid + 128] + red[tid + 192]) / S;
    __syncthreads();

    // ---- out[b] = kbar @ Wv
    acc = 0.f;
    #pragma unroll
    for (int i = 0; i < 16; ++i) {
        const int dd = wave * 16 + i;
        acc += vec[dd] * Wv[dd * 64 + lane];
    }
    red[tid] = acc;
    __syncthreads();
    if (tid < 64)
        out[(size_t)b * 64 + tid] = red[tid] + red[tid + 64] + red[tid + 128] + red[tid + 192];
}
} // namespace

extern "C" void kernel_launch(void* const* d_in, const int* in_sizes, int n_in,
                              void* d_out, int out_size, void* d_ws, size_t ws_size,
                              hipStream_t stream) {
    const float* q    = (const float*)d_in[0];
    const float* k    = (const float*)d_in[1];
    // d_in[2] = v : unused by the reference (vp is computed from k)
    const int*   kes  = (const int*)  d_in[3];
    const float* fs   = (const float*)d_in[4];
    const float* bias = (const float*)d_in[5];
    const float* Wq   = (const float*)d_in[6];
    const float* Wk   = (const float*)d_in[7];
    const float* Wv   = (const float*)d_in[8];
    float* out = (float*)d_out;

    auto_attn_kernel<<<dim3(1024), dim3(256), 0, stream>>>(q, k, kes, fs, bias, Wq, Wk, Wv, out);
}